// Round 2
// baseline (267.722 us; speedup 1.0000x reference)
//
#include <hip/hip_runtime.h>
#include <math.h>

// Problem constants (from reference)
#define GAMMA 0.98f
#define LBDA  0.93f
#define GL    (GAMMA * LBDA)   // gamma*lambda
constexpr int B  = 2048;
constexpr int T  = 1024;
constexpr int NT = B * T;      // 2,097,152

// ---------------------------------------------------------------------------
// log_pi = x[a] - logsumexp(x[0..5])
// ---------------------------------------------------------------------------
__device__ __forceinline__ float logpi(float x0, float x1, float x2,
                                       float x3, float x4, float x5, int a) {
    float m = fmaxf(fmaxf(fmaxf(x0, x1), fmaxf(x2, x3)), fmaxf(x4, x5));
    float s = __expf(x0 - m) + __expf(x1 - m) + __expf(x2 - m) +
              __expf(x3 - m) + __expf(x4 - m) + __expf(x5 - m);
    float lse = m + __logf(s);
    float r = x0;
    r = (a == 1) ? x1 : r;
    r = (a == 2) ? x2 : r;
    r = (a == 3) ? x3 : r;
    r = (a == 4) ? x4 : r;
    r = (a == 5) ? x5 : r;
    return r - lse;
}

// LDS float4-index swizzle: conflict-free for both stride-1 writes
// (permutes within aligned-8 groups) and stride-3 reads (lanes 8 apart,
// whose indices differ by 24, get 8 distinct quad-banks via the XOR term).
__device__ __forceinline__ int sw(int m) { return m ^ ((m >> 3) & 7); }

// ---------------------------------------------------------------------------
// Kernel 1: log-softmax gather. Block stages 512 elements (768 float4 = 12KB)
// of logits through LDS with coalesced stride-1 global loads; same buffer is
// reused for logits_old. Thread t computes element pair (2p, 2p+1).
// Writes ratio r=exp(lp-lpo) to rbuf; block-reduces entropy sum into acc[0].
// ---------------------------------------------------------------------------
__global__ __launch_bounds__(256) void k_elem(
        const float4* __restrict__ lg, const float4* __restrict__ lgo,
        const int2* __restrict__ act, float2* __restrict__ rbuf,
        float* __restrict__ acc) {
    int tid = threadIdx.x;
    int p = blockIdx.x * 256 + tid;            // element-pair index
    const float4* s0 = lg  + blockIdx.x * 768;
    const float4* s1 = lgo + blockIdx.x * 768;

    // coalesced global loads, both arrays hoisted for latency overlap
    float4 g0 = s0[tid], g1 = s0[tid + 256], g2 = s0[tid + 512];
    float4 h0 = s1[tid], h1 = s1[tid + 256], h2 = s1[tid + 512];
    int2 aa = act[p];

    __shared__ float4 sb[768];
    sb[sw(tid)] = g0; sb[sw(tid + 256)] = g1; sb[sw(tid + 512)] = g2;
    __syncthreads();
    float4 A0 = sb[sw(3 * tid)], A1 = sb[sw(3 * tid + 1)], A2 = sb[sw(3 * tid + 2)];
    float lp0 = logpi(A0.x, A0.y, A0.z, A0.w, A1.x, A1.y, aa.x);
    float lp1 = logpi(A1.z, A1.w, A2.x, A2.y, A2.z, A2.w, aa.y);
    __syncthreads();

    sb[sw(tid)] = h0; sb[sw(tid + 256)] = h1; sb[sw(tid + 512)] = h2;
    __syncthreads();
    float4 B0 = sb[sw(3 * tid)], B1 = sb[sw(3 * tid + 1)], B2 = sb[sw(3 * tid + 2)];
    float lpo0 = logpi(B0.x, B0.y, B0.z, B0.w, B1.x, B1.y, aa.x);
    float lpo1 = logpi(B1.z, B1.w, B2.x, B2.y, B2.z, B2.w, aa.y);

    rbuf[p] = make_float2(__expf(lp0 - lpo0), __expf(lp1 - lpo1));

    // block-reduce entropy sum
    float es = lp0 + lp1;
    #pragma unroll
    for (int d = 32; d; d >>= 1) es += __shfl_xor(es, d);
    __shared__ float sm[4];
    int lane = tid & 63;
    if (lane == 0) sm[tid >> 6] = es;
    __syncthreads();
    if (tid == 0) atomicAdd(acc + 0, sm[0] + sm[1] + sm[2] + sm[3]);
}

// ---------------------------------------------------------------------------
// Kernel 2: one block (256 threads) per batch row. Thread j owns timesteps
// t = 4j..4j+3 (coalesced float4 loads). Both reverse recurrences
//   Rs[t] = base1[t] + c1[t]*Rs[t+1]   (returns)
//   A[t]  = base2[t] + c2[t]*A[t+1]    (GAE)
// solved via affine-map suffix composition: per-thread local map -> wave
// Hillis-Steele suffix scan -> 4-wave LDS fixup -> replay with exact carry,
// accumulating value/ppo loss sums. Last-arriving block finalizes d_out.
// ---------------------------------------------------------------------------
__global__ __launch_bounds__(256) void k_scan(
        const float4* __restrict__ rw4, const float4* __restrict__ vl4,
        const int4* __restrict__ dn4, const float4* __restrict__ rr4,
        float* __restrict__ acc, float* __restrict__ out) {
    int j = threadIdx.x;
    int base = blockIdx.x * 256 + j;
    float4 rw = rw4[base], vl = vl4[base], rr = rr4[base];
    int4 dn = dn4[base];

    __shared__ float sv[256];
    __shared__ float wa1[4], wb1[4], wa2[4], wb2[4];
    __shared__ float red[8];

    sv[j] = vl.x;                 // values at t = 4j
    __syncthreads();
    float vnext = (j < 255) ? sv[j + 1] : 0.0f;   // values[4j+4] (unused j=255)

    float rwk[4] = {rw.x, rw.y, rw.z, rw.w};
    float vk[5]  = {vl.x, vl.y, vl.z, vl.w, vnext};
    int   dk[4]  = {dn.x, dn.y, dn.z, dn.w};

    float b1[4], c1[4], b2[4], c2[4];
    #pragma unroll
    for (int k = 0; k < 4; ++k) {
        bool d = dk[k] != 0;
        c1[k] = d ? 0.0f : GAMMA;
        b1[k] = rwk[k];
        c2[k] = d ? 0.0f : GL;
        b2[k] = rwk[k] + (d ? 0.0f : GAMMA * vk[k + 1]) - vk[k];  // td error
    }
    if (j == 255) {  // t = T-1 special: Rs[T-1] = d ? r : v ; A[T-1] = 0
        b1[3] = dk[3] ? rwk[3] : vk[3];
        c1[3] = 0.0f;
        b2[3] = 0.0f;
        c2[3] = 0.0f;
    }

    // local suffix composition over k = 3..0
    float a1 = 1.0f, bb1 = 0.0f, a2 = 1.0f, bb2 = 0.0f;
    #pragma unroll
    for (int k = 3; k >= 0; --k) {
        bb1 = b1[k] + c1[k] * bb1;  a1 = c1[k] * a1;
        bb2 = b2[k] + c2[k] * bb2;  a2 = c2[k] * a2;
    }

    // wave-level inclusive SUFFIX scan of affine maps
    int lane = j & 63, wv = j >> 6;
    #pragma unroll
    for (int d = 1; d < 64; d <<= 1) {
        float an1 = __shfl_down(a1, d), bn1 = __shfl_down(bb1, d);
        float an2 = __shfl_down(a2, d), bn2 = __shfl_down(bb2, d);
        if (lane + d < 64) {
            bb1 = a1 * bn1 + bb1;  a1 = a1 * an1;
            bb2 = a2 * bn2 + bb2;  a2 = a2 * an2;
        }
    }
    if (lane == 0) { wa1[wv] = a1; wb1[wv] = bb1; wa2[wv] = a2; wb2[wv] = bb2; }
    // neighbor's suffix map S_{j+1}
    float a1s = __shfl_down(a1, 1), b1s = __shfl_down(bb1, 1);
    float a2s = __shfl_down(a2, 1), b2s = __shfl_down(bb2, 1);
    __syncthreads();

    // carry entering this wave's high end
    float x1 = 0.0f, x2 = 0.0f;
    for (int w2 = 3; w2 > wv; --w2) {
        x1 = wa1[w2] * x1 + wb1[w2];
        x2 = wa2[w2] * x2 + wb2[w2];
    }
    // carry entering this thread (state at t = 4j+4)
    float cin1 = (lane == 63) ? x1 : (a1s * x1 + b1s);
    float cin2 = (lane == 63) ? x2 : (a2s * x2 + b2s);

    // replay with exact carries, accumulate losses
    float rrk[4] = {rr.x, rr.y, rr.z, rr.w};
    float vsum = 0.0f, psum = 0.0f;
    float R = cin1, A = cin2;
    #pragma unroll
    for (int k = 3; k >= 0; --k) {
        R = b1[k] + c1[k] * R;
        float dv = R - vk[k];
        vsum += dv * dv;
        A = b2[k] + c2[k] * A;
        if (4 * j + k < T - 1) {
            // faithful torch clip(min=0.8,max=0.2) -> r_clipped == 0.2
            psum += fminf(rrk[k] * A, 0.2f * A);
        }
    }

    #pragma unroll
    for (int d = 32; d; d >>= 1) {
        vsum += __shfl_xor(vsum, d);
        psum += __shfl_xor(psum, d);
    }
    if (lane == 0) { red[wv] = vsum; red[4 + wv] = psum; }
    __syncthreads();
    if (j == 0) {
        atomicAdd(acc + 1, red[0] + red[1] + red[2] + red[3]);
        atomicAdd(acc + 2, red[4] + red[5] + red[6] + red[7]);
        __threadfence();
        unsigned old = atomicAdd((unsigned*)(acc + 3), 1u);
        if (old == (unsigned)(B - 1)) {
            // last block: all k_elem (stream-ordered) and k_scan atomics done
            float e = atomicAdd(acc + 0, 0.0f);
            float v = atomicAdd(acc + 1, 0.0f);
            float pp = atomicAdd(acc + 2, 0.0f);
            out[0] = -pp / (float)(B * (T - 1));   // ppo_loss
            out[1] =  v  / (float)(B * T);         // value_loss
            out[2] = -e  / (float)(B * T);         // entropy_loss
        }
    }
}

// ---------------------------------------------------------------------------
extern "C" void kernel_launch(void* const* d_in, const int* in_sizes, int n_in,
                              void* d_out, int out_size, void* d_ws, size_t ws_size,
                              hipStream_t stream) {
    const float* rewards    = (const float*)d_in[0];
    const float* values     = (const float*)d_in[1];
    const float* logits     = (const float*)d_in[2];
    const float* logits_old = (const float*)d_in[3];
    const int*   dones      = (const int*)d_in[4];
    const int*   actions    = (const int*)d_in[5];

    float* acc  = (float*)d_ws;   // [0]=entropy, [1]=value, [2]=ppo, [3]=counter
    float* rbuf = acc + 4;        // ratio buffer, NT floats (8 MB), 16B aligned

    hipMemsetAsync(d_ws, 0, 4 * sizeof(float), stream);

    k_elem<<<NT / 2 / 256, 256, 0, stream>>>(
        (const float4*)logits, (const float4*)logits_old,
        (const int2*)actions, (float2*)rbuf, acc);

    k_scan<<<B, 256, 0, stream>>>(
        (const float4*)rewards, (const float4*)values,
        (const int4*)dones, (const float4*)rbuf, acc, (float*)d_out);
}

// Round 3
// 166.739 us; speedup vs baseline: 1.6056x; 1.6056x over previous
//
#include <hip/hip_runtime.h>
#include <math.h>

// Problem constants (from reference)
#define GAMMA 0.98f
#define LBDA  0.93f
#define GL    (GAMMA * LBDA)   // gamma*lambda
constexpr int B  = 2048;
constexpr int T  = 1024;
constexpr int NT = B * T;      // 2,097,152
constexpr int NBLK_E = NT / 2 / 256;   // 4096 k_elem blocks

// ---------------------------------------------------------------------------
// log_pi = x[a] - logsumexp(x[0..5])
// ---------------------------------------------------------------------------
__device__ __forceinline__ float logpi(float x0, float x1, float x2,
                                       float x3, float x4, float x5, int a) {
    float m = fmaxf(fmaxf(fmaxf(x0, x1), fmaxf(x2, x3)), fmaxf(x4, x5));
    float s = __expf(x0 - m) + __expf(x1 - m) + __expf(x2 - m) +
              __expf(x3 - m) + __expf(x4 - m) + __expf(x5 - m);
    float lse = m + __logf(s);
    float r = x0;
    r = (a == 1) ? x1 : r;
    r = (a == 2) ? x2 : r;
    r = (a == 3) ? x3 : r;
    r = (a == 4) ? x4 : r;
    r = (a == 5) ? x5 : r;
    return r - lse;
}

// LDS float4-index swizzle: conflict-free for stride-1 writes and stride-3 reads.
__device__ __forceinline__ int sw(int m) { return m ^ ((m >> 3) & 7); }

// ---------------------------------------------------------------------------
// Kernel 1: log-softmax gather. Block stages 768 contiguous float4 (12KB) of
// logits through LDS (coalesced global loads), reuses buffer for logits_old.
// Writes ratio r=exp(lp-lpo) to rbuf; block entropy partial -> part_e[blk]
// (plain store, no contended atomics).
// ---------------------------------------------------------------------------
__global__ __launch_bounds__(256) void k_elem(
        const float4* __restrict__ lg, const float4* __restrict__ lgo,
        const int2* __restrict__ act, float2* __restrict__ rbuf,
        float* __restrict__ part_e) {
    int tid = threadIdx.x;
    int p = blockIdx.x * 256 + tid;            // element-pair index
    const float4* s0 = lg  + blockIdx.x * 768;
    const float4* s1 = lgo + blockIdx.x * 768;

    float4 g0 = s0[tid], g1 = s0[tid + 256], g2 = s0[tid + 512];
    float4 h0 = s1[tid], h1 = s1[tid + 256], h2 = s1[tid + 512];
    int2 aa = act[p];

    __shared__ float4 sb[768];
    sb[sw(tid)] = g0; sb[sw(tid + 256)] = g1; sb[sw(tid + 512)] = g2;
    __syncthreads();
    float4 A0 = sb[sw(3 * tid)], A1 = sb[sw(3 * tid + 1)], A2 = sb[sw(3 * tid + 2)];
    float lp0 = logpi(A0.x, A0.y, A0.z, A0.w, A1.x, A1.y, aa.x);
    float lp1 = logpi(A1.z, A1.w, A2.x, A2.y, A2.z, A2.w, aa.y);
    __syncthreads();

    sb[sw(tid)] = h0; sb[sw(tid + 256)] = h1; sb[sw(tid + 512)] = h2;
    __syncthreads();
    float4 B0 = sb[sw(3 * tid)], B1 = sb[sw(3 * tid + 1)], B2 = sb[sw(3 * tid + 2)];
    float lpo0 = logpi(B0.x, B0.y, B0.z, B0.w, B1.x, B1.y, aa.x);
    float lpo1 = logpi(B1.z, B1.w, B2.x, B2.y, B2.z, B2.w, aa.y);

    rbuf[p] = make_float2(__expf(lp0 - lpo0), __expf(lp1 - lpo1));

    // block-reduce entropy partial -> private slot (no atomic)
    float es = lp0 + lp1;
    #pragma unroll
    for (int d = 32; d; d >>= 1) es += __shfl_xor(es, d);
    __shared__ float sm[4];
    int lane = tid & 63;
    if (lane == 0) sm[tid >> 6] = es;
    __syncthreads();
    if (tid == 0) part_e[blockIdx.x] = sm[0] + sm[1] + sm[2] + sm[3];
}

// ---------------------------------------------------------------------------
// Kernel 2: one block (256 threads) per batch row. Thread j owns timesteps
// t = 4j..4j+3. Reverse recurrences (returns Rs, GAE A) solved via affine-map
// suffix composition: local map -> wave Hillis-Steele suffix scan -> 4-wave
// LDS fixup -> replay with exact carry. Partials -> part_v/part_p[blk].
// ---------------------------------------------------------------------------
__global__ __launch_bounds__(256) void k_scan(
        const float4* __restrict__ rw4, const float4* __restrict__ vl4,
        const int4* __restrict__ dn4, const float4* __restrict__ rr4,
        float* __restrict__ part_v, float* __restrict__ part_p) {
    int j = threadIdx.x;
    int base = blockIdx.x * 256 + j;
    float4 rw = rw4[base], vl = vl4[base], rr = rr4[base];
    int4 dn = dn4[base];

    __shared__ float sv[256];
    __shared__ float wa1[4], wb1[4], wa2[4], wb2[4];
    __shared__ float red[8];

    sv[j] = vl.x;                 // values at t = 4j
    __syncthreads();
    float vnext = (j < 255) ? sv[j + 1] : 0.0f;   // values[4j+4] (unused j=255)

    float rwk[4] = {rw.x, rw.y, rw.z, rw.w};
    float vk[5]  = {vl.x, vl.y, vl.z, vl.w, vnext};
    int   dk[4]  = {dn.x, dn.y, dn.z, dn.w};

    float b1[4], c1[4], b2[4], c2[4];
    #pragma unroll
    for (int k = 0; k < 4; ++k) {
        bool d = dk[k] != 0;
        c1[k] = d ? 0.0f : GAMMA;
        b1[k] = rwk[k];
        c2[k] = d ? 0.0f : GL;
        b2[k] = rwk[k] + (d ? 0.0f : GAMMA * vk[k + 1]) - vk[k];  // td error
    }
    if (j == 255) {  // t = T-1: Rs[T-1] = d ? r : v ; A[T-1] = 0
        b1[3] = dk[3] ? rwk[3] : vk[3];
        c1[3] = 0.0f;
        b2[3] = 0.0f;
        c2[3] = 0.0f;
    }

    // local suffix composition over k = 3..0
    float a1 = 1.0f, bb1 = 0.0f, a2 = 1.0f, bb2 = 0.0f;
    #pragma unroll
    for (int k = 3; k >= 0; --k) {
        bb1 = b1[k] + c1[k] * bb1;  a1 = c1[k] * a1;
        bb2 = b2[k] + c2[k] * bb2;  a2 = c2[k] * a2;
    }

    // wave-level inclusive SUFFIX scan of affine maps
    int lane = j & 63, wv = j >> 6;
    #pragma unroll
    for (int d = 1; d < 64; d <<= 1) {
        float an1 = __shfl_down(a1, d), bn1 = __shfl_down(bb1, d);
        float an2 = __shfl_down(a2, d), bn2 = __shfl_down(bb2, d);
        if (lane + d < 64) {
            bb1 = a1 * bn1 + bb1;  a1 = a1 * an1;
            bb2 = a2 * bn2 + bb2;  a2 = a2 * an2;
        }
    }
    if (lane == 0) { wa1[wv] = a1; wb1[wv] = bb1; wa2[wv] = a2; wb2[wv] = bb2; }
    float a1s = __shfl_down(a1, 1), b1s = __shfl_down(bb1, 1);
    float a2s = __shfl_down(a2, 1), b2s = __shfl_down(bb2, 1);
    __syncthreads();

    // carry entering this wave's high end
    float x1 = 0.0f, x2 = 0.0f;
    for (int w2 = 3; w2 > wv; --w2) {
        x1 = wa1[w2] * x1 + wb1[w2];
        x2 = wa2[w2] * x2 + wb2[w2];
    }
    float cin1 = (lane == 63) ? x1 : (a1s * x1 + b1s);
    float cin2 = (lane == 63) ? x2 : (a2s * x2 + b2s);

    // replay with exact carries, accumulate losses
    float rrk[4] = {rr.x, rr.y, rr.z, rr.w};
    float vsum = 0.0f, psum = 0.0f;
    float R = cin1, A = cin2;
    #pragma unroll
    for (int k = 3; k >= 0; --k) {
        R = b1[k] + c1[k] * R;
        float dv = R - vk[k];
        vsum += dv * dv;
        A = b2[k] + c2[k] * A;
        if (4 * j + k < T - 1) {
            // faithful torch clip(min=0.8,max=0.2) -> r_clipped == 0.2
            psum += fminf(rrk[k] * A, 0.2f * A);
        }
    }

    #pragma unroll
    for (int d = 32; d; d >>= 1) {
        vsum += __shfl_xor(vsum, d);
        psum += __shfl_xor(psum, d);
    }
    if (lane == 0) { red[wv] = vsum; red[4 + wv] = psum; }
    __syncthreads();
    if (j == 0) {
        part_v[blockIdx.x] = red[0] + red[1] + red[2] + red[3];
        part_p[blockIdx.x] = red[4] + red[5] + red[6] + red[7];
    }
}

// ---------------------------------------------------------------------------
// Kernel 3: single-block reduction of all partials -> 3 outputs.
// ---------------------------------------------------------------------------
__global__ __launch_bounds__(256) void k_fin(
        const float* __restrict__ part_e, const float* __restrict__ part_v,
        const float* __restrict__ part_p, float* __restrict__ out) {
    int tid = threadIdx.x;
    float e = 0.0f, v = 0.0f, p = 0.0f;
    for (int i = tid; i < NBLK_E; i += 256) e += part_e[i];
    for (int i = tid; i < B; i += 256)      v += part_v[i];
    for (int i = tid; i < B; i += 256)      p += part_p[i];
    #pragma unroll
    for (int d = 32; d; d >>= 1) {
        e += __shfl_xor(e, d);
        v += __shfl_xor(v, d);
        p += __shfl_xor(p, d);
    }
    __shared__ float sm[12];
    int lane = tid & 63, wv = tid >> 6;
    if (lane == 0) { sm[wv] = e; sm[4 + wv] = v; sm[8 + wv] = p; }
    __syncthreads();
    if (tid == 0) {
        float te = sm[0] + sm[1] + sm[2] + sm[3];
        float tv = sm[4] + sm[5] + sm[6] + sm[7];
        float tp = sm[8] + sm[9] + sm[10] + sm[11];
        out[0] = -tp / (float)(B * (T - 1));   // ppo_loss
        out[1] =  tv / (float)(B * T);         // value_loss
        out[2] = -te / (float)(B * T);         // entropy_loss
    }
}

// ---------------------------------------------------------------------------
extern "C" void kernel_launch(void* const* d_in, const int* in_sizes, int n_in,
                              void* d_out, int out_size, void* d_ws, size_t ws_size,
                              hipStream_t stream) {
    const float* rewards    = (const float*)d_in[0];
    const float* values     = (const float*)d_in[1];
    const float* logits     = (const float*)d_in[2];
    const float* logits_old = (const float*)d_in[3];
    const int*   dones      = (const int*)d_in[4];
    const int*   actions    = (const int*)d_in[5];

    float* rbuf   = (float*)d_ws;          // NT floats (8 MB), 16B aligned
    float* part_e = rbuf + NT;             // 4096 floats
    float* part_v = part_e + NBLK_E;       // 2048 floats
    float* part_p = part_v + B;            // 2048 floats

    k_elem<<<NBLK_E, 256, 0, stream>>>(
        (const float4*)logits, (const float4*)logits_old,
        (const int2*)actions, (float2*)rbuf, part_e);

    k_scan<<<B, 256, 0, stream>>>(
        (const float4*)rewards, (const float4*)values,
        (const int4*)dones, (const float4*)rbuf, part_v, part_p);

    k_fin<<<1, 256, 0, stream>>>(part_e, part_v, part_p, (float*)d_out);
}

// Round 4
// 155.953 us; speedup vs baseline: 1.7167x; 1.0692x over previous
//
#include <hip/hip_runtime.h>
#include <math.h>

// Problem constants (from reference)
#define GAMMA 0.98f
#define LBDA  0.93f
#define GL    (GAMMA * LBDA)   // gamma*lambda
constexpr int B  = 2048;
constexpr int T  = 1024;

// ---------------------------------------------------------------------------
// log_pi = x[a] - logsumexp(x[0..5])
// ---------------------------------------------------------------------------
__device__ __forceinline__ float logpi(float x0, float x1, float x2,
                                       float x3, float x4, float x5, int a) {
    float m = fmaxf(fmaxf(fmaxf(x0, x1), fmaxf(x2, x3)), fmaxf(x4, x5));
    float s = __expf(x0 - m) + __expf(x1 - m) + __expf(x2 - m) +
              __expf(x3 - m) + __expf(x4 - m) + __expf(x5 - m);
    float lse = m + __logf(s);
    float r = x0;
    r = (a == 1) ? x1 : r;
    r = (a == 2) ? x2 : r;
    r = (a == 3) ? x3 : r;
    r = (a == 4) ? x4 : r;
    r = (a == 5) ? x5 : r;
    return r - lse;
}

// LDS float4-index swizzle: conflict-free for stride-1 writes and stride-3
// reads (validated: SQ_LDS_BANK_CONFLICT == 0 in rounds 2-3).
__device__ __forceinline__ int sw(int m) { return m ^ ((m >> 3) & 7); }

// ---------------------------------------------------------------------------
// Fused kernel: one block (512 threads) per batch row; thread j owns
// timesteps t = 2j, 2j+1.
//  1. Stage row's logits (1536 float4 = 24KB) via LDS (coalesced, swizzled),
//     compute log_pi; restage logits_old, compute log_pi_old; r in registers.
//  2. Reverse recurrences (returns Rs, GAE A) via affine-map suffix
//     composition: local map -> wave suffix scan -> 8-wave LDS fixup ->
//     replay with exact carry.
//  3. Block-reduce entropy/value/ppo partials -> private slots (no atomics).
// ---------------------------------------------------------------------------
__global__ __launch_bounds__(512) void k_fused(
        const float2* __restrict__ rw2, const float2* __restrict__ vl2,
        const int2* __restrict__ dn2, const int2* __restrict__ ac2,
        const float4* __restrict__ lg4, const float4* __restrict__ lgo4,
        float* __restrict__ part_e, float* __restrict__ part_v,
        float* __restrict__ part_p) {
    int j = threadIdx.x;
    int b = blockIdx.x;

    const float4* Lrow = lg4  + (size_t)b * 1536;   // 1536 float4 per row
    const float4* Orow = lgo4 + (size_t)b * 1536;
    int rbase = b * 512 + j;                        // float2/int2 row index

    // hoisted coalesced global loads (latency overlap)
    float4 g0 = Lrow[j], g1 = Lrow[j + 512], g2 = Lrow[j + 1024];
    float4 h0 = Orow[j], h1 = Orow[j + 512], h2 = Orow[j + 1024];
    float2 rw = rw2[rbase], vl = vl2[rbase];
    int2 dn = dn2[rbase], aa = ac2[rbase];

    __shared__ float4 sb[1536];                     // 24 KB staging
    __shared__ float sv[512];
    __shared__ float wa1[8], wb1[8], wa2[8], wb2[8];
    __shared__ float red[24];

    sv[j] = vl.x;                                   // values at t = 2j
    sb[sw(j)] = g0; sb[sw(j + 512)] = g1; sb[sw(j + 1024)] = g2;
    __syncthreads();
    float4 A0 = sb[sw(3 * j)], A1 = sb[sw(3 * j + 1)], A2 = sb[sw(3 * j + 2)];
    float vnext = (j < 511) ? sv[j + 1] : 0.0f;     // values[2j+2]
    float lp0 = logpi(A0.x, A0.y, A0.z, A0.w, A1.x, A1.y, aa.x);
    float lp1 = logpi(A1.z, A1.w, A2.x, A2.y, A2.z, A2.w, aa.y);
    __syncthreads();
    sb[sw(j)] = h0; sb[sw(j + 512)] = h1; sb[sw(j + 1024)] = h2;
    __syncthreads();
    float4 B0 = sb[sw(3 * j)], B1 = sb[sw(3 * j + 1)], B2 = sb[sw(3 * j + 2)];
    float lpo0 = logpi(B0.x, B0.y, B0.z, B0.w, B1.x, B1.y, aa.x);
    float lpo1 = logpi(B1.z, B1.w, B2.x, B2.y, B2.z, B2.w, aa.y);

    float rr0 = __expf(lp0 - lpo0), rr1 = __expf(lp1 - lpo1);

    // ---- per-thread affine maps for the two recurrences -------------------
    float rwk[2] = {rw.x, rw.y};
    float vk[3]  = {vl.x, vl.y, vnext};
    int   dk[2]  = {dn.x, dn.y};

    float b1[2], c1[2], b2[2], c2[2];
    #pragma unroll
    for (int k = 0; k < 2; ++k) {
        bool d = dk[k] != 0;
        c1[k] = d ? 0.0f : GAMMA;
        b1[k] = rwk[k];
        c2[k] = d ? 0.0f : GL;
        b2[k] = rwk[k] + (d ? 0.0f : GAMMA * vk[k + 1]) - vk[k];  // td error
    }
    if (j == 511) {  // t = T-1: Rs[T-1] = d ? r : v ; A[T-1] = 0
        b1[1] = dk[1] ? rwk[1] : vk[1];
        c1[1] = 0.0f;
        b2[1] = 0.0f;
        c2[1] = 0.0f;
    }

    // local suffix composition over k = 1..0
    float a1 = 1.0f, bb1 = 0.0f, a2 = 1.0f, bb2 = 0.0f;
    #pragma unroll
    for (int k = 1; k >= 0; --k) {
        bb1 = b1[k] + c1[k] * bb1;  a1 = c1[k] * a1;
        bb2 = b2[k] + c2[k] * bb2;  a2 = c2[k] * a2;
    }

    // wave-level inclusive SUFFIX scan of affine maps
    int lane = j & 63, wv = j >> 6;
    #pragma unroll
    for (int d = 1; d < 64; d <<= 1) {
        float an1 = __shfl_down(a1, d), bn1 = __shfl_down(bb1, d);
        float an2 = __shfl_down(a2, d), bn2 = __shfl_down(bb2, d);
        if (lane + d < 64) {
            bb1 = a1 * bn1 + bb1;  a1 = a1 * an1;
            bb2 = a2 * bn2 + bb2;  a2 = a2 * an2;
        }
    }
    if (lane == 0) { wa1[wv] = a1; wb1[wv] = bb1; wa2[wv] = a2; wb2[wv] = bb2; }
    float a1s = __shfl_down(a1, 1), b1s = __shfl_down(bb1, 1);
    float a2s = __shfl_down(a2, 1), b2s = __shfl_down(bb2, 1);
    __syncthreads();

    // carry entering this wave's high end (apply later waves' maps to 0)
    float x1 = 0.0f, x2 = 0.0f;
    for (int w2 = 7; w2 > wv; --w2) {
        x1 = wa1[w2] * x1 + wb1[w2];
        x2 = wa2[w2] * x2 + wb2[w2];
    }
    float cin1 = (lane == 63) ? x1 : (a1s * x1 + b1s);
    float cin2 = (lane == 63) ? x2 : (a2s * x2 + b2s);

    // replay with exact carries, accumulate losses
    float rrk[2] = {rr0, rr1};
    float vsum = 0.0f, psum = 0.0f;
    float R = cin1, A = cin2;
    #pragma unroll
    for (int k = 1; k >= 0; --k) {
        R = b1[k] + c1[k] * R;
        float dv = R - vk[k];
        vsum += dv * dv;
        A = b2[k] + c2[k] * A;
        if (2 * j + k < T - 1) {
            // faithful torch clip(min=0.8,max=0.2) -> r_clipped == 0.2
            psum += fminf(rrk[k] * A, 0.2f * A);
        }
    }
    float es = lp0 + lp1;

    #pragma unroll
    for (int d = 32; d; d >>= 1) {
        es   += __shfl_xor(es, d);
        vsum += __shfl_xor(vsum, d);
        psum += __shfl_xor(psum, d);
    }
    if (lane == 0) { red[wv] = es; red[8 + wv] = vsum; red[16 + wv] = psum; }
    __syncthreads();
    if (j == 0) {
        float te = 0.0f, tv = 0.0f, tp = 0.0f;
        #pragma unroll
        for (int w2 = 0; w2 < 8; ++w2) {
            te += red[w2]; tv += red[8 + w2]; tp += red[16 + w2];
        }
        part_e[b] = te;
        part_v[b] = tv;
        part_p[b] = tp;
    }
}

// ---------------------------------------------------------------------------
// Finalize: single-block reduction of 3 x B partials -> 3 outputs.
// ---------------------------------------------------------------------------
__global__ __launch_bounds__(256) void k_fin(
        const float* __restrict__ part_e, const float* __restrict__ part_v,
        const float* __restrict__ part_p, float* __restrict__ out) {
    int tid = threadIdx.x;
    float e = 0.0f, v = 0.0f, p = 0.0f;
    for (int i = tid; i < B; i += 256) {
        e += part_e[i];
        v += part_v[i];
        p += part_p[i];
    }
    #pragma unroll
    for (int d = 32; d; d >>= 1) {
        e += __shfl_xor(e, d);
        v += __shfl_xor(v, d);
        p += __shfl_xor(p, d);
    }
    __shared__ float sm[12];
    int lane = tid & 63, wv = tid >> 6;
    if (lane == 0) { sm[wv] = e; sm[4 + wv] = v; sm[8 + wv] = p; }
    __syncthreads();
    if (tid == 0) {
        float te = sm[0] + sm[1] + sm[2] + sm[3];
        float tv = sm[4] + sm[5] + sm[6] + sm[7];
        float tp = sm[8] + sm[9] + sm[10] + sm[11];
        out[0] = -tp / (float)(B * (T - 1));   // ppo_loss
        out[1] =  tv / (float)(B * T);         // value_loss
        out[2] = -te / (float)(B * T);         // entropy_loss
    }
}

// ---------------------------------------------------------------------------
extern "C" void kernel_launch(void* const* d_in, const int* in_sizes, int n_in,
                              void* d_out, int out_size, void* d_ws, size_t ws_size,
                              hipStream_t stream) {
    const float* rewards    = (const float*)d_in[0];
    const float* values     = (const float*)d_in[1];
    const float* logits     = (const float*)d_in[2];
    const float* logits_old = (const float*)d_in[3];
    const int*   dones      = (const int*)d_in[4];
    const int*   actions    = (const int*)d_in[5];

    float* part_e = (float*)d_ws;       // B floats
    float* part_v = part_e + B;         // B floats
    float* part_p = part_v + B;         // B floats

    k_fused<<<B, 512, 0, stream>>>(
        (const float2*)rewards, (const float2*)values,
        (const int2*)dones, (const int2*)actions,
        (const float4*)logits, (const float4*)logits_old,
        part_e, part_v, part_p);

    k_fin<<<1, 256, 0, stream>>>(part_e, part_v, part_p, (float*)d_out);
}